// Round 11
// baseline (764.676 us; speedup 1.0000x reference)
//
#include <hip/hip_runtime.h>
#include <stdint.h>

#define N_T 32768
#define N_Q 4096
#define E_T 1048576
#define E_Q 131072
#define H   128
#define NL  3
#define VOCAB 1001

typedef float    f32x4 __attribute__((ext_vector_type(4)));
typedef int      i32x4 __attribute__((ext_vector_type(4)));
typedef _Float16 f16x8 __attribute__((ext_vector_type(8)));

__device__ __forceinline__ ushort f2h(float x){
  union{_Float16 h; ushort u;} c; c.h = (_Float16)x; return c.u;
}
__device__ __forceinline__ float h2f(unsigned u){
  union{ushort u; _Float16 h;} c; c.u = (ushort)u; return (float)c.h;
}

// ---------------- fused init: zero counters/rowsum + detect mask + convert W/emb ----------------
// blocks 0..511: cnt_t (4*N_T ints); 512..527: cnt_q; 528..543: rowsum;
// 544: flag+detect; 545..640: weight cvt; 641..703: emb cvt
__global__ void init_k(int* cnt_t, int* cnt_q, float* rowsum, int* flag,
                       const unsigned* m,
                       const float* __restrict__ Wl, const float* __restrict__ Wr,
                       ushort* __restrict__ WH, ushort* __restrict__ WLo,
                       const float* __restrict__ emb, ushort* __restrict__ emb16){
  int b = blockIdx.x, t = threadIdx.x;
  if(b < 512){ cnt_t[b*256+t] = 0; }
  else if(b < 528){ cnt_q[(b-512)*256+t] = 0; }
  else if(b < 544){ rowsum[(b-528)*256+t] = 0.f; }
  else if(b == 544){
    if(t == 0) *flag = 0;
    __syncthreads();
    int f = 0;
    for(int j=t;j<4096;j+=256){
      unsigned v = m[j];
      if(v > 1u) f |= (v & 0xFEFEFEFEu) ? 2 : 1;
    }
    if(f) atomicOr(flag, f);
  }
  else if(b < 641){
    int i = (b-545)*256 + t;           // NL*128*64 = 24576
    int k  = (i & 63) * 4;
    int c  = (i >> 6) & 127;
    int l  = i >> 13;
    const float* src = (k < 128)
        ? &Wl[((size_t)l*128 + c)*128 + k]
        : &Wr[((size_t)l*128 + c)*128 + (k-128)];
    float4 v = *(const float4*)src;
    ushort4 h, lo;
    h.x = f2h(v.x); lo.x = f2h(v.x - h2f(h.x));
    h.y = f2h(v.y); lo.y = f2h(v.y - h2f(h.y));
    h.z = f2h(v.z); lo.z = f2h(v.z - h2f(h.z));
    h.w = f2h(v.w); lo.w = f2h(v.w - h2f(h.w));
    size_t off = ((size_t)l*128 + c)*256 + k;
    *(ushort4*)&WH[off]  = h;
    *(ushort4*)&WLo[off] = lo;
  } else {
    int i = (b-641)*256 + t;           // VOCAB*H/8 = 16016
    if(i >= VOCAB*H/8) return;
    float4 v0 = ((const float4*)emb)[(size_t)i*2];
    float4 v1 = ((const float4*)emb)[(size_t)i*2 + 1];
    uint4 u;
    u.x = (unsigned)f2h(v0.x) | ((unsigned)f2h(v0.y)<<16);
    u.y = (unsigned)f2h(v0.z) | ((unsigned)f2h(v0.w)<<16);
    u.z = (unsigned)f2h(v1.x) | ((unsigned)f2h(v1.y)<<16);
    u.w = (unsigned)f2h(v1.z) | ((unsigned)f2h(v1.w)<<16);
    ((uint4*)emb16)[i] = u;
  }
}

// ---------------- CSR build; t-graph bucketed by src quarter (L2 locality) ----------------
__global__ void count2_k(const int* __restrict__ te, const int* __restrict__ qe,
                         int* cnt_t, int* cnt_q){
  int b = blockIdx.x;
  if(b < E_T/256){
    int i = b*256 + threadIdx.x;
    int dst = te[E_T + i], src = te[i];
    atomicAdd(&cnt_t[(dst<<2) | (src>>13)], 1);
  } else {
    int i = (b - E_T/256)*256 + threadIdx.x;
    atomicAdd(&cnt_q[qe[E_Q + i]], 1);
  }
}

__device__ __forceinline__ void scan_body(const int* cnt, int n, int* rp, int* pos){
  __shared__ int part[1024];
  int t = threadIdx.x;
  int chunk = (n + 1023) >> 10;
  int lo = t*chunk, hi = lo+chunk; if(hi>n) hi=n;
  int s = 0;
  int i = lo;
  for(; i+4 <= hi; i+=4){
    i32x4 v = *(const i32x4*)&cnt[i];
    s += v[0]+v[1]+v[2]+v[3];
  }
  for(; i < hi; i++) s += cnt[i];
  part[t] = s;
  __syncthreads();
  for(int off=1; off<1024; off<<=1){
    int v = (t >= off) ? part[t-off] : 0;
    __syncthreads();
    part[t] += v;
    __syncthreads();
  }
  int run = (t==0) ? 0 : part[t-1];
  i = lo;
  for(; i+4 <= hi; i+=4){
    i32x4 v = *(const i32x4*)&cnt[i];
    rp[i]=run;   pos[i]=run;   run += v[0];
    rp[i+1]=run; pos[i+1]=run; run += v[1];
    rp[i+2]=run; pos[i+2]=run; run += v[2];
    rp[i+3]=run; pos[i+3]=run; run += v[3];
  }
  for(; i < hi; i++){ rp[i]=run; pos[i]=run; run += cnt[i]; }
  if(t==0) rp[n] = part[1023];
}

__global__ void scan2_k(const int* cnt_t, int* rp_t, int* pos_t,
                        const int* cnt_q, int* rp_q, int* pos_q){
  if(blockIdx.x == 0) scan_body(cnt_t, 4*N_T, rp_t, pos_t);
  else                scan_body(cnt_q, N_Q, rp_q, pos_q);
}

__global__ void fill2_k(const int* __restrict__ te, const int* __restrict__ qe,
                        int* pos_t, int* csr_t, int* pos_q, int* csr_q){
  int b = blockIdx.x;
  if(b < E_T/256){
    int i = b*256 + threadIdx.x;
    int dst = te[E_T + i], src = te[i];
    int p = atomicAdd(&pos_t[(dst<<2) | (src>>13)], 1);
    csr_t[p] = src;
  } else {
    int i = (b - E_T/256)*256 + threadIdx.x;
    int p = atomicAdd(&pos_q[qe[E_Q + i]], 1);
    csr_q[p] = qe[i];
  }
}

// ---------------- segment mean (fp16 features; layer0 via emb16[nid]) ----------------
__device__ __forceinline__ void agg_body(const ushort* x, const int* nid,
    const ushort* emb16, const int* csr, ushort* agg,
    int wid, int rs, int re, int lane){
  const unsigned* xw = (const unsigned*)x;
  const unsigned* ew = (const unsigned*)emb16;
  float px[8], py[8];
  #pragma unroll
  for(int q=0;q<8;q++){ px[q]=0.f; py[q]=0.f; }
  int j = rs;
  if(nid){
    for(; j+8 <= re; j+=8){
      #pragma unroll
      for(int q=0;q<8;q++){
        unsigned u = ew[(size_t)nid[csr[j+q]]*64 + lane];
        px[q] += h2f(u & 0xFFFFu); py[q] += h2f(u >> 16);
      }
    }
    for(; j < re; j++){
      unsigned u = ew[(size_t)nid[csr[j]]*64 + lane];
      px[0] += h2f(u & 0xFFFFu); py[0] += h2f(u >> 16);
    }
  } else {
    for(; j+8 <= re; j+=8){
      #pragma unroll
      for(int q=0;q<8;q++){
        unsigned u = xw[(size_t)csr[j+q]*64 + lane];
        px[q] += h2f(u & 0xFFFFu); py[q] += h2f(u >> 16);
      }
    }
    for(; j < re; j++){
      unsigned u = xw[(size_t)csr[j]*64 + lane];
      px[0] += h2f(u & 0xFFFFu); py[0] += h2f(u >> 16);
    }
  }
  float sx = ((px[0]+px[1]) + (px[2]+px[3])) + ((px[4]+px[5]) + (px[6]+px[7]));
  float sy = ((py[0]+py[1]) + (py[2]+py[3])) + ((py[4]+py[5]) + (py[6]+py[7]));
  int c = re - rs; if(c < 1) c = 1;
  float inv = 1.0f / (float)c;
  ((unsigned*)agg)[(size_t)wid*64 + lane] =
      (unsigned)f2h(sx*inv) | ((unsigned)f2h(sy*inv) << 16);
}

__global__ void agg2_k(const ushort* xt, const ushort* xq,
                       const int* nidt, const int* nidq, const ushort* emb16,
                       const int* __restrict__ rp_t, const int* __restrict__ csr_t,
                       const int* __restrict__ rp_q, const int* __restrict__ csr_q,
                       ushort* aggt, ushort* aggq){
  int b = blockIdx.x;
  int lane = threadIdx.x & 63;
  int wv = threadIdx.x >> 6;
  if(b < N_T/4){
    int wid = b*4 + wv;
    // t-CSR is (dst, src-quarter) bucketed: flat range covers 4 sub-buckets in order
    agg_body(xt, nidt, emb16, csr_t, aggt, wid, rp_t[wid*4], rp_t[wid*4+4], lane);
  } else {
    int wid = (b - N_T/4)*4 + wv;
    agg_body(xq, nidq, emb16, csr_q, aggq, wid, rp_q[wid], rp_q[wid+1], lane);
  }
}

// ---------------- layer GEMM (MFMA), both graphs: out = elu([agg|x] @ [Wl|Wr]^T + bl) ----------------
__global__ __launch_bounds__(256,3) void layer2_k(
    const ushort* __restrict__ aggT, const ushort* __restrict__ xT,
    const int* __restrict__ nidT, ushort* __restrict__ outT,
    const ushort* __restrict__ aggQ, const ushort* __restrict__ xQ,
    const int* __restrict__ nidQ, ushort* __restrict__ outQ,
    const ushort* __restrict__ emb16,
    const ushort* __restrict__ WH, const ushort* __restrict__ WLo,
    const float* __restrict__ bl){
  __shared__ ushort SM3[3*128*64];     // SA | SH | SL (48 KB); reused as LT
  ushort* SA = SM3;
  ushort* SH = SM3 + 8192;
  ushort* SL = SM3 + 16384;
  int bq = (int)blockIdx.x - (N_T/128);
  const ushort* agg   = (bq < 0) ? aggT : aggQ;
  const ushort* xprev = (bq < 0) ? xT   : xQ;
  const int*    nid   = (bq < 0) ? nidT : nidQ;
  ushort*       out16 = (bq < 0) ? outT : outQ;
  int r0g = ((bq < 0) ? (int)blockIdx.x : bq) * 128;
  int t = threadIdx.x;
  int lane = t & 63;
  int w = t >> 6;
  int wr = w >> 1, wc = w & 1;
  int fr = lane & 15, kg0 = lane >> 4;
  f32x4 acc[4][4] = {};
  for(int kt=0; kt<4; kt++){
    __syncthreads();
    int ko = (kt & 1) * 64;
    #pragma unroll
    for(int it=0; it<4; it++){
      int idx = t + it*256;            // 0..1023
      int row = idx >> 3, k8 = idx & 7;
      int sw = (k8 ^ (row & 7)) * 8;
      uint4 av;
      if(kt < 2){
        av = *(const uint4*)&agg[(size_t)(r0g+row)*H + ko + k8*8];
      } else if(nid){
        av = *(const uint4*)&emb16[(size_t)nid[r0g+row]*H + ko + k8*8];
      } else {
        av = *(const uint4*)&xprev[(size_t)(r0g+row)*H + ko + k8*8];
      }
      *(uint4*)&SA[row*64 + sw] = av;
      *(uint4*)&SH[row*64 + sw] = *(const uint4*)&WH[row*256 + kt*64 + k8*8];
      *(uint4*)&SL[row*64 + sw] = *(const uint4*)&WLo[row*256 + kt*64 + k8*8];
    }
    __syncthreads();
    #pragma unroll
    for(int s=0; s<2; s++){
      int kg = s*4 + kg0;
      f16x8 a[4], bh[4], blo[4];
      #pragma unroll
      for(int m=0;m<4;m++){
        int ar = wr*64 + m*16 + fr;
        a[m] = *(const f16x8*)&SA[ar*64 + ((kg ^ (ar & 7)) << 3)];
      }
      #pragma unroll
      for(int n=0;n<4;n++){
        int bc = wc*64 + n*16 + fr;
        int ib = bc*64 + ((kg ^ (bc & 7)) << 3);
        bh[n]  = *(const f16x8*)&SH[ib];
        blo[n] = *(const f16x8*)&SL[ib];
      }
      #pragma unroll
      for(int m=0;m<4;m++)
        #pragma unroll
        for(int n=0;n<4;n++){
          acc[m][n] = __builtin_amdgcn_mfma_f32_16x16x32_f16(a[m], bh[n],  acc[m][n], 0,0,0);
          acc[m][n] = __builtin_amdgcn_mfma_f32_16x16x32_f16(a[m], blo[n], acc[m][n], 0,0,0);
        }
    }
  }
  __syncthreads();
  ushort* LT = SM3;                    // 128*128 ushort = 32 KB
  #pragma unroll
  for(int n=0;n<4;n++){
    int c = wc*64 + n*16 + fr;
    float b = bl[c];
    #pragma unroll
    for(int m=0;m<4;m++){
      int r = wr*64 + m*16 + kg0*4;
      #pragma unroll
      for(int reg=0;reg<4;reg++){
        float v = acc[m][n][reg] + b;
        v = (v > 0.f) ? v : expm1f(v);
        LT[(r+reg)*128 + c] = f2h(v);
      }
    }
  }
  __syncthreads();
  #pragma unroll
  for(int i=0;i<8;i++){
    int idx = t + i*256;               // 0..2047
    int row = idx >> 4, c8 = idx & 15;
    *(uint4*)&out16[(size_t)(r0g+row)*H + c8*8] = *(uint4*)&LT[row*128 + c8*8];
  }
}

// ---------------- attention helpers ----------------
__device__ __forceinline__ unsigned nib8(unsigned x, unsigned y){
  unsigned r = (x & 0xFu) | ((x>>4)&0xF0u) | ((x>>8)&0xF00u) | ((x>>12)&0xF000u);
  unsigned s = (y & 0xFu) | ((y>>4)&0xF0u) | ((y>>8)&0xF00u) | ((y>>12)&0xF000u);
  return r | (s<<16);
}
__device__ __forceinline__ unsigned pk4(unsigned u){
  return ((u & 0xFFu)       ? 1u : 0u) | ((u & 0xFF00u)     ? 2u : 0u)
       | ((u & 0xFF0000u)   ? 4u : 0u) | ((u & 0xFF000000u) ? 8u : 0u);
}

// stage 128x128 raw mask tile -> MB[512] packed bits (coalesced, NT loads, no ballot).
__device__ __forceinline__ void stage_mask_tile(const void* maskp, int mb,
    int gr0, int gc0, unsigned* MB, uint8_t* NB, unsigned* bitsOut, int t){
  if(mb & 2){
    const f32x4* base = (const f32x4*)maskp;
    #pragma unroll
    for(int i=0;i<16;i++){
      int idx = i*256 + t;
      int row = idx >> 5, c4 = idx & 31;
      f32x4 v = __builtin_nontemporal_load(
          &base[((size_t)(gr0+row)*N_T + gc0) / 4 + c4]);
      NB[row*32 + c4] = (uint8_t)((unsigned)(v[0]!=0.f) | ((unsigned)(v[1]!=0.f)<<1)
                                | ((unsigned)(v[2]!=0.f)<<2) | ((unsigned)(v[3]!=0.f)<<3));
    }
  } else if(mb & 1){
    const uint8_t* base = (const uint8_t*)maskp;
    #pragma unroll
    for(int i=0;i<16;i++){
      int idx = i*256 + t;
      int row = idx >> 5, c4 = idx & 31;
      unsigned u = __builtin_nontemporal_load(
          (const unsigned*)&base[(size_t)(gr0+row)*N_T + gc0 + c4*4]);
      NB[row*32 + c4] = (uint8_t)pk4(u);
    }
  } else {
    const i32x4* base = (const i32x4*)maskp;
    #pragma unroll
    for(int i=0;i<16;i++){
      int idx = i*256 + t;
      int row = idx >> 5, c4 = idx & 31;
      i32x4 v = __builtin_nontemporal_load(
          &base[((size_t)(gr0+row)*N_T + gc0) / 4 + c4]);
      NB[row*32 + c4] = (uint8_t)((unsigned)(v[0]!=0) | ((unsigned)(v[1]!=0)<<1)
                                | ((unsigned)(v[2]!=0)<<2) | ((unsigned)(v[3]!=0)<<3));
    }
  }
  __syncthreads();
  if(t < 128){
    uint4 a = *(const uint4*)&NB[t*32];
    uint4 b = *(const uint4*)&NB[t*32 + 16];
    unsigned w0 = nib8(a.x, a.y), w1 = nib8(a.z, a.w);
    unsigned w2 = nib8(b.x, b.y), w3 = nib8(b.z, b.w);
    MB[t*4]   = w0; MB[t*4+1] = w1;
    MB[t*4+2] = w2; MB[t*4+3] = w3;
    if(bitsOut){
      uint4 o; o.x=w0; o.y=w1; o.z=w2; o.w=w3;
      *(uint4*)&bitsOut[(size_t)(gr0 + t)*(N_T/32) + (gc0 >> 5)] = o;
    }
  }
}

// XCD-aware tile decode: each XCD owns a 32-tile et column panel (1 MB, L2-fit)
__device__ __forceinline__ void att_tile(int bid, int& gc0, int& gr0){
  int xcd = bid & 7;
  int idx = bid >> 3;
  gc0 = (xcd*32 + (idx & 31)) * 128;
  gr0 = (idx >> 5) * 128;
}

// fp16 S^T GEMM core: A = et (M=target), B = eq (N=query). 128x128 tile, 4 waves.
__device__ __forceinline__ void qk_gemm(
    const ushort* __restrict__ A16, const ushort* __restrict__ B16,
    int abase, int bbase, int t, ushort* SM, f32x4 (&acc)[4][4]){
  ushort* AB = SM;            // [128][64] swizzled
  ushort* BB = SM + 8192;
  int lane = t & 63;
  int w = t >> 6;
  int wr = w >> 1, wc = w & 1;
  int fr = lane & 15, kg0 = lane >> 4;
  for(int kt=0; kt<2; kt++){
    __syncthreads();
    #pragma unroll
    for(int it=0; it<4; it++){
      int idx = t + it*256;          // 0..1023
      int row = idx >> 3, k8 = idx & 7;
      int sw = (k8 ^ (row & 7)) * 8;
      *(uint4*)&AB[row*64 + sw] = *(const uint4*)&A16[(size_t)(abase+row)*H + kt*64 + k8*8];
      *(uint4*)&BB[row*64 + sw] = *(const uint4*)&B16[(size_t)(bbase+row)*H + kt*64 + k8*8];
    }
    __syncthreads();
    #pragma unroll
    for(int s=0; s<2; s++){
      int kg = s*4 + kg0;
      f16x8 a[4], b[4];
      #pragma unroll
      for(int m=0;m<4;m++){
        int ar = wr*64 + m*16 + fr;
        a[m] = *(const f16x8*)&AB[ar*64 + ((kg ^ (ar & 7)) << 3)];
      }
      #pragma unroll
      for(int n=0;n<4;n++){
        int bc = wc*64 + n*16 + fr;
        b[n] = *(const f16x8*)&BB[bc*64 + ((kg ^ (bc & 7)) << 3)];
      }
      #pragma unroll
      for(int m=0;m<4;m++)
        #pragma unroll
        for(int n=0;n<4;n++)
          acc[m][n] = __builtin_amdgcn_mfma_f32_16x16x32_f16(a[m], b[n], acc[m][n], 0,0,0);
    }
  }
}

// ---------------- attention pass A: raw mask -> bits, GEMM, rowsums ----------------
__global__ __launch_bounds__(256,4) void attsum_k(
    const ushort* __restrict__ eq16, const ushort* __restrict__ et16,
    const void* __restrict__ maskp, const int* __restrict__ flag,
    unsigned* __restrict__ bitsOut, float* __restrict__ rowsum){
  __shared__ ushort SM[2*128*64];       // 32 KB (first 4KB aliased as nibble staging)
  __shared__ __align__(16) unsigned MB[512];
  __shared__ float RS[128][2];
  int t = threadIdx.x;
  int gc0, gr0;
  att_tile(blockIdx.x, gc0, gr0);
  int lane = t & 63;
  int w = t >> 6;
  int wr = w >> 1, wc = w & 1;
  int fr = lane & 15, kg0 = lane >> 4;

  int mb = *flag;
  stage_mask_tile(maskp, mb, gr0, gc0, MB, (uint8_t*)SM, bitsOut, t);

  f32x4 acc[4][4] = {};
  qk_gemm(et16, eq16, gc0, gr0, t, SM, acc);

  const float sc = 0.08838834764831845f;   // 1/sqrt(128)
  #pragma unroll
  for(int n=0;n<4;n++){
    int q = wc*64 + n*16 + fr;
    float s = 0.f;
    #pragma unroll
    for(int m=0;m<4;m++){
      unsigned wb = MB[q*4 + wr*2 + (m>>1)];
      int off = ((m&1)<<4) | (kg0<<2);
      s += ((wb>>(off+0))&1u) ? __expf(acc[m][n][0]*sc) : 0.f;
      s += ((wb>>(off+1))&1u) ? __expf(acc[m][n][1]*sc) : 0.f;
      s += ((wb>>(off+2))&1u) ? __expf(acc[m][n][2]*sc) : 0.f;
      s += ((wb>>(off+3))&1u) ? __expf(acc[m][n][3]*sc) : 0.f;
    }
    s += __shfl_xor(s, 16);
    s += __shfl_xor(s, 32);
    if(lane < 16) RS[q][wr] = s;
  }
  __syncthreads();
  if(t < 128) atomicAdd(&rowsum[gr0 + t], RS[t][0] + RS[t][1]);
}

// ---------------- attention pass B: recompute, normalize, NT float4 store ----------------
__global__ __launch_bounds__(256,4) void attout_k(
    const ushort* __restrict__ eq16, const ushort* __restrict__ et16,
    const void* __restrict__ maskp, const int* __restrict__ flag,
    const unsigned* __restrict__ bitsIn, const float* __restrict__ rowsum,
    float* __restrict__ out){
  __shared__ ushort SM[2*128*64];
  __shared__ __align__(16) unsigned MB[512];
  __shared__ float IRS[128];
  int t = threadIdx.x;
  int gc0, gr0;
  att_tile(blockIdx.x, gc0, gr0);
  int lane = t & 63;
  int w = t >> 6;
  int wr = w >> 1, wc = w & 1;
  int fr = lane & 15, kg0 = lane >> 4;

  if(bitsIn){
    if(t < 128)
      *(uint4*)&MB[t*4] = *(const uint4*)&bitsIn[(size_t)(gr0 + t)*(N_T/32) + (gc0 >> 5)];
  } else {
    int mb = *flag;
    stage_mask_tile(maskp, mb, gr0, gc0, MB, (uint8_t*)SM, nullptr, t);
  }
  if(t < 128) IRS[t] = 1.0f / rowsum[gr0 + t];

  f32x4 acc[4][4] = {};
  qk_gemm(et16, eq16, gc0, gr0, t, SM, acc);

  const float sc = 0.08838834764831845f;
  #pragma unroll
  for(int n=0;n<4;n++){
    int q = wc*64 + n*16 + fr;
    float ir = IRS[q];
    size_t rb = (size_t)(gr0 + q)*N_T + gc0 + wr*64;
    #pragma unroll
    for(int m=0;m<4;m++){
      unsigned wb = MB[q*4 + wr*2 + (m>>1)];
      int off = ((m&1)<<4) | (kg0<<2);
      f32x4 o;
      o[0] = ((wb>>(off+0))&1u) ? __expf(acc[m][n][0]*sc)*ir : 0.f;
      o[1] = ((wb>>(off+1))&1u) ? __expf(acc[m][n][1]*sc)*ir : 0.f;
      o[2] = ((wb>>(off+2))&1u) ? __expf(acc[m][n][2]*sc)*ir : 0.f;
      o[3] = ((wb>>(off+3))&1u) ? __expf(acc[m][n][3]*sc)*ir : 0.f;
      __builtin_nontemporal_store(o, (f32x4*)&out[rb + m*16 + (kg0<<2)]);
    }
  }
}

// ---------------- host launch ----------------
extern "C" void kernel_launch(void* const* d_in, const int* in_sizes, int n_in,
                              void* d_out, int out_size, void* d_ws, size_t ws_size,
                              hipStream_t stream){
  const int* tx  = (const int*)d_in[0];
  const int* qx  = (const int*)d_in[1];
  const int* te  = (const int*)d_in[2];
  const int* qe  = (const int*)d_in[3];
  const void* mask = d_in[4];
  const float* emb = (const float*)d_in[5];
  const float* Wl  = (const float*)d_in[6];
  const float* bl  = (const float*)d_in[7];
  const float* Wr  = (const float*)d_in[8];
  float* out = (float*)d_out;

  // ws layout: features @0, rowsum/flag @9MB, weights @10MB, emb16 @11MB, bits @19MB
  ushort* et16 = (ushort*)d_ws;                       // N_T*H (8 MB)
  ushort* eq16 = et16 + (size_t)N_T*H;                // N_Q*H (1 MB)
  float* rowsum = (float*)((char*)d_ws + ((size_t)9 << 20));
  int*   flag   = (int*)(rowsum + N_Q);
  ushort* WH  = (ushort*)((char*)d_ws + ((size_t)10 << 20));   // NL*128*256 (192 KB)
  ushort* WLo = WH + (size_t)NL*128*256;
  ushort* emb16 = (ushort*)((char*)d_ws + ((size_t)11 << 20)); // VOCAB*H fp16 (256 KB)
  bool useBits = ws_size >= ((size_t)37 << 20);
  unsigned* bits = useBits ? (unsigned*)((char*)d_ws + ((size_t)19 << 20)) : nullptr;

  // phase-1 scratch inside d_out (512MB; fully overwritten by attout at the end)
  char* S = (char*)d_out;
  ushort* xt0  = (ushort*)(S);                         // 8 MB (layer0 out)
  ushort* xt1  = (ushort*)(S + 8388608);               // 8 MB (layer1 out)
  ushort* aggt = (ushort*)(S + 16777216);              // 8 MB
  ushort* xq0  = (ushort*)(S + 25165824);              // 1 MB
  ushort* xq1  = (ushort*)(S + 26214400);              // 1 MB
  ushort* aggq = (ushort*)(S + 27262976);              // 1 MB
  int*   cnt_t = (int*)(S + 28311552);                 // 4*N_T ints (src-quarter buckets)
  int*   rp_t  = cnt_t + 4*N_T;                        // 4*N_T+1
  int*   pos_t = rp_t + 4*N_T + 1;                     // 4*N_T
  int*   csr_t = pos_t + 4*N_T;                        // E_T
  int*   cnt_q = csr_t + E_T;
  int*   rp_q  = cnt_q + N_Q;
  int*   pos_q = rp_q + N_Q + 1;
  int*   csr_q = pos_q + N_Q;

  init_k<<<704,256,0,stream>>>(cnt_t, cnt_q, rowsum, flag, (const unsigned*)mask,
                               Wl, Wr, WH, WLo, emb, emb16);
  count2_k<<<E_T/256 + E_Q/256,256,0,stream>>>(te, qe, cnt_t, cnt_q);
  scan2_k<<<2,1024,0,stream>>>(cnt_t, rp_t, pos_t, cnt_q, rp_q, pos_q);
  fill2_k<<<E_T/256 + E_Q/256,256,0,stream>>>(te, qe, pos_t, csr_t, pos_q, csr_q);

  ushort* outs_t[NL] = {xt0, xt1, et16};
  ushort* outs_q[NL] = {xq0, xq1, eq16};
  const ushort* cur_t = nullptr;
  const ushort* cur_q = nullptr;
  for(int l=0;l<NL;l++){
    const ushort* wh = WH  + (size_t)l*128*256;
    const ushort* wl = WLo + (size_t)l*128*256;
    const int* nidt = (l==0) ? tx : nullptr;
    const int* nidq = (l==0) ? qx : nullptr;
    agg2_k<<<N_T/4 + N_Q/4,256,0,stream>>>(cur_t, cur_q, nidt, nidq, emb16,
                                           rp_t, csr_t, rp_q, csr_q, aggt, aggq);
    layer2_k<<<N_T/128 + N_Q/128,256,0,stream>>>(aggt, cur_t, nidt, outs_t[l],
                                                 aggq, cur_q, nidq, outs_q[l],
                                                 emb16, wh, wl, bl+(size_t)l*H);
    cur_t = outs_t[l];
    cur_q = outs_q[l];
  }

  attsum_k<<<8192,256,0,stream>>>(eq16, et16, mask, flag, bits, rowsum);
  attout_k<<<8192,256,0,stream>>>(eq16, et16, mask, flag, bits, rowsum, out);
}

// Round 12
// 616.869 us; speedup vs baseline: 1.2396x; 1.2396x over previous
//
#include <hip/hip_runtime.h>
#include <stdint.h>

#define N_T 32768
#define N_Q 4096
#define E_T 1048576
#define E_Q 131072
#define H   128
#define NL  3
#define VOCAB 1001

typedef float    f32x4 __attribute__((ext_vector_type(4)));
typedef int      i32x4 __attribute__((ext_vector_type(4)));
typedef _Float16 f16x8 __attribute__((ext_vector_type(8)));

__device__ __forceinline__ ushort f2h(float x){
  union{_Float16 h; ushort u;} c; c.h = (_Float16)x; return c.u;
}
__device__ __forceinline__ float h2f(unsigned u){
  union{ushort u; _Float16 h;} c; c.u = (ushort)u; return (float)c.h;
}

// ---------------- fused init: zero counters/rowsum + detect mask + convert W/emb ----------------
// blocks 0..127: cnt_t; 128..143: cnt_q; 144..159: rowsum; 160: flag+detect;
// 161..256: weight cvt (96); 257..319: emb cvt (63)
__global__ void init_k(int* cnt_t, int* cnt_q, float* rowsum, int* flag,
                       const unsigned* m,
                       const float* __restrict__ Wl, const float* __restrict__ Wr,
                       ushort* __restrict__ WH, ushort* __restrict__ WLo,
                       const float* __restrict__ emb, ushort* __restrict__ emb16){
  int b = blockIdx.x, t = threadIdx.x;
  if(b < 128){ cnt_t[b*256+t] = 0; }
  else if(b < 144){ cnt_q[(b-128)*256+t] = 0; }
  else if(b < 160){ rowsum[(b-144)*256+t] = 0.f; }
  else if(b == 160){
    if(t == 0) *flag = 0;
    __syncthreads();
    int f = 0;
    for(int j=t;j<4096;j+=256){
      unsigned v = m[j];
      if(v > 1u) f |= (v & 0xFEFEFEFEu) ? 2 : 1;
    }
    if(f) atomicOr(flag, f);
  }
  else if(b < 257){
    int i = (b-161)*256 + t;           // NL*128*64 = 24576
    int k  = (i & 63) * 4;
    int c  = (i >> 6) & 127;
    int l  = i >> 13;
    const float* src = (k < 128)
        ? &Wl[((size_t)l*128 + c)*128 + k]
        : &Wr[((size_t)l*128 + c)*128 + (k-128)];
    float4 v = *(const float4*)src;
    ushort4 h, lo;
    h.x = f2h(v.x); lo.x = f2h(v.x - h2f(h.x));
    h.y = f2h(v.y); lo.y = f2h(v.y - h2f(h.y));
    h.z = f2h(v.z); lo.z = f2h(v.z - h2f(h.z));
    h.w = f2h(v.w); lo.w = f2h(v.w - h2f(h.w));
    size_t off = ((size_t)l*128 + c)*256 + k;
    *(ushort4*)&WH[off]  = h;
    *(ushort4*)&WLo[off] = lo;
  } else {
    int i = (b-257)*256 + t;           // VOCAB*H/8 = 16016
    if(i >= VOCAB*H/8) return;
    float4 v0 = ((const float4*)emb)[(size_t)i*2];
    float4 v1 = ((const float4*)emb)[(size_t)i*2 + 1];
    uint4 u;
    u.x = (unsigned)f2h(v0.x) | ((unsigned)f2h(v0.y)<<16);
    u.y = (unsigned)f2h(v0.z) | ((unsigned)f2h(v0.w)<<16);
    u.z = (unsigned)f2h(v1.x) | ((unsigned)f2h(v1.y)<<16);
    u.w = (unsigned)f2h(v1.z) | ((unsigned)f2h(v1.w)<<16);
    ((uint4*)emb16)[i] = u;
  }
}

// ---------------- CSR build (both graphs per launch) ----------------
__global__ void count2_k(const int* __restrict__ te, const int* __restrict__ qe,
                         int* cnt_t, int* cnt_q){
  int b = blockIdx.x;
  if(b < E_T/256){
    int i = b*256 + threadIdx.x;
    atomicAdd(&cnt_t[te[E_T + i]], 1);
  } else {
    int i = (b - E_T/256)*256 + threadIdx.x;
    atomicAdd(&cnt_q[qe[E_Q + i]], 1);
  }
}

__device__ __forceinline__ void scan_body(const int* cnt, int n, int* rp, int* pos){
  __shared__ int part[1024];
  int t = threadIdx.x;
  int chunk = (n + 1023) >> 10;
  int lo = t*chunk, hi = lo+chunk; if(hi>n) hi=n;
  int s = 0;
  int i = lo;
  for(; i+4 <= hi; i+=4){
    i32x4 v = *(const i32x4*)&cnt[i];
    s += v[0]+v[1]+v[2]+v[3];
  }
  for(; i < hi; i++) s += cnt[i];
  part[t] = s;
  __syncthreads();
  for(int off=1; off<1024; off<<=1){
    int v = (t >= off) ? part[t-off] : 0;
    __syncthreads();
    part[t] += v;
    __syncthreads();
  }
  int run = (t==0) ? 0 : part[t-1];
  i = lo;
  for(; i+4 <= hi; i+=4){
    i32x4 v = *(const i32x4*)&cnt[i];
    rp[i]=run;   pos[i]=run;   run += v[0];
    rp[i+1]=run; pos[i+1]=run; run += v[1];
    rp[i+2]=run; pos[i+2]=run; run += v[2];
    rp[i+3]=run; pos[i+3]=run; run += v[3];
  }
  for(; i < hi; i++){ rp[i]=run; pos[i]=run; run += cnt[i]; }
  if(t==0) rp[n] = part[1023];
}

__global__ void scan2_k(const int* cnt_t, int* rp_t, int* pos_t,
                        const int* cnt_q, int* rp_q, int* pos_q){
  if(blockIdx.x == 0) scan_body(cnt_t, N_T, rp_t, pos_t);
  else                scan_body(cnt_q, N_Q, rp_q, pos_q);
}

__global__ void fill2_k(const int* __restrict__ te, const int* __restrict__ qe,
                        int* pos_t, int* csr_t, int* pos_q, int* csr_q){
  int b = blockIdx.x;
  if(b < E_T/256){
    int i = b*256 + threadIdx.x;
    int p = atomicAdd(&pos_t[te[E_T + i]], 1);
    csr_t[p] = te[i];
  } else {
    int i = (b - E_T/256)*256 + threadIdx.x;
    int p = atomicAdd(&pos_q[qe[E_Q + i]], 1);
    csr_q[p] = qe[i];
  }
}

// ---------------- segment mean, both graphs (fp16 features; layer0 via emb16[nid]) ----------------
__device__ __forceinline__ void agg_body(const ushort* x, const int* nid,
    const ushort* emb16, const int* rp, const int* csr, ushort* agg,
    int wid, int lane){
  const unsigned* xw = (const unsigned*)x;
  const unsigned* ew = (const unsigned*)emb16;
  int rs = rp[wid], re = rp[wid+1];
  float px[8], py[8];
  #pragma unroll
  for(int q=0;q<8;q++){ px[q]=0.f; py[q]=0.f; }
  int j = rs;
  if(nid){
    for(; j+8 <= re; j+=8){
      #pragma unroll
      for(int q=0;q<8;q++){
        unsigned u = ew[(size_t)nid[csr[j+q]]*64 + lane];
        px[q] += h2f(u & 0xFFFFu); py[q] += h2f(u >> 16);
      }
    }
    for(; j < re; j++){
      unsigned u = ew[(size_t)nid[csr[j]]*64 + lane];
      px[0] += h2f(u & 0xFFFFu); py[0] += h2f(u >> 16);
    }
  } else {
    for(; j+8 <= re; j+=8){
      #pragma unroll
      for(int q=0;q<8;q++){
        unsigned u = xw[(size_t)csr[j+q]*64 + lane];
        px[q] += h2f(u & 0xFFFFu); py[q] += h2f(u >> 16);
      }
    }
    for(; j < re; j++){
      unsigned u = xw[(size_t)csr[j]*64 + lane];
      px[0] += h2f(u & 0xFFFFu); py[0] += h2f(u >> 16);
    }
  }
  float sx = ((px[0]+px[1]) + (px[2]+px[3])) + ((px[4]+px[5]) + (px[6]+px[7]));
  float sy = ((py[0]+py[1]) + (py[2]+py[3])) + ((py[4]+py[5]) + (py[6]+py[7]));
  int c = re - rs; if(c < 1) c = 1;
  float inv = 1.0f / (float)c;
  ((unsigned*)agg)[(size_t)wid*64 + lane] =
      (unsigned)f2h(sx*inv) | ((unsigned)f2h(sy*inv) << 16);
}

__global__ void agg2_k(const ushort* xt, const ushort* xq,
                       const int* nidt, const int* nidq, const ushort* emb16,
                       const int* rp_t, const int* csr_t,
                       const int* rp_q, const int* csr_q,
                       ushort* aggt, ushort* aggq){
  int b = blockIdx.x;
  int lane = threadIdx.x & 63;
  int wv = threadIdx.x >> 6;
  if(b < N_T/4){
    agg_body(xt, nidt, emb16, rp_t, csr_t, aggt, b*4 + wv, lane);
  } else {
    agg_body(xq, nidq, emb16, rp_q, csr_q, aggq, (b - N_T/4)*4 + wv, lane);
  }
}

// ---------------- layer GEMM (MFMA), both graphs: out = elu([agg|x] @ [Wl|Wr]^T + bl) ----------------
__global__ __launch_bounds__(256,3) void layer2_k(
    const ushort* __restrict__ aggT, const ushort* __restrict__ xT,
    const int* __restrict__ nidT, ushort* __restrict__ outT,
    const ushort* __restrict__ aggQ, const ushort* __restrict__ xQ,
    const int* __restrict__ nidQ, ushort* __restrict__ outQ,
    const ushort* __restrict__ emb16,
    const ushort* __restrict__ WH, const ushort* __restrict__ WLo,
    const float* __restrict__ bl){
  __shared__ ushort SM3[3*128*64];     // SA | SH | SL (48 KB); reused as LT
  ushort* SA = SM3;
  ushort* SH = SM3 + 8192;
  ushort* SL = SM3 + 16384;
  int bq = (int)blockIdx.x - (N_T/128);
  const ushort* agg   = (bq < 0) ? aggT : aggQ;
  const ushort* xprev = (bq < 0) ? xT   : xQ;
  const int*    nid   = (bq < 0) ? nidT : nidQ;
  ushort*       out16 = (bq < 0) ? outT : outQ;
  int r0g = ((bq < 0) ? (int)blockIdx.x : bq) * 128;
  int t = threadIdx.x;
  int lane = t & 63;
  int w = t >> 6;
  int wr = w >> 1, wc = w & 1;
  int fr = lane & 15, kg0 = lane >> 4;
  f32x4 acc[4][4] = {};
  for(int kt=0; kt<4; kt++){
    __syncthreads();
    int ko = (kt & 1) * 64;
    #pragma unroll
    for(int it=0; it<4; it++){
      int idx = t + it*256;            // 0..1023
      int row = idx >> 3, k8 = idx & 7;
      int sw = (k8 ^ (row & 7)) * 8;
      uint4 av;
      if(kt < 2){
        av = *(const uint4*)&agg[(size_t)(r0g+row)*H + ko + k8*8];
      } else if(nid){
        av = *(const uint4*)&emb16[(size_t)nid[r0g+row]*H + ko + k8*8];
      } else {
        av = *(const uint4*)&xprev[(size_t)(r0g+row)*H + ko + k8*8];
      }
      *(uint4*)&SA[row*64 + sw] = av;
      *(uint4*)&SH[row*64 + sw] = *(const uint4*)&WH[row*256 + kt*64 + k8*8];
      *(uint4*)&SL[row*64 + sw] = *(const uint4*)&WLo[row*256 + kt*64 + k8*8];
    }
    __syncthreads();
    #pragma unroll
    for(int s=0; s<2; s++){
      int kg = s*4 + kg0;
      f16x8 a[4], bh[4], blo[4];
      #pragma unroll
      for(int m=0;m<4;m++){
        int ar = wr*64 + m*16 + fr;
        a[m] = *(const f16x8*)&SA[ar*64 + ((kg ^ (ar & 7)) << 3)];
      }
      #pragma unroll
      for(int n=0;n<4;n++){
        int bc = wc*64 + n*16 + fr;
        int ib = bc*64 + ((kg ^ (bc & 7)) << 3);
        bh[n]  = *(const f16x8*)&SH[ib];
        blo[n] = *(const f16x8*)&SL[ib];
      }
      #pragma unroll
      for(int m=0;m<4;m++)
        #pragma unroll
        for(int n=0;n<4;n++){
          acc[m][n] = __builtin_amdgcn_mfma_f32_16x16x32_f16(a[m], bh[n],  acc[m][n], 0,0,0);
          acc[m][n] = __builtin_amdgcn_mfma_f32_16x16x32_f16(a[m], blo[n], acc[m][n], 0,0,0);
        }
    }
  }
  __syncthreads();
  ushort* LT = SM3;                    // 128*128 ushort = 32 KB
  #pragma unroll
  for(int n=0;n<4;n++){
    int c = wc*64 + n*16 + fr;
    float b = bl[c];
    #pragma unroll
    for(int m=0;m<4;m++){
      int r = wr*64 + m*16 + kg0*4;
      #pragma unroll
      for(int reg=0;reg<4;reg++){
        float v = acc[m][n][reg] + b;
        v = (v > 0.f) ? v : expm1f(v);
        LT[(r+reg)*128 + c] = f2h(v);
      }
    }
  }
  __syncthreads();
  #pragma unroll
  for(int i=0;i<8;i++){
    int idx = t + i*256;               // 0..2047
    int row = idx >> 4, c8 = idx & 15;
    *(uint4*)&out16[(size_t)(r0g+row)*H + c8*8] = *(uint4*)&LT[row*128 + c8*8];
  }
}

// ---------------- attention helpers ----------------
__device__ __forceinline__ unsigned nib8(unsigned x, unsigned y){
  unsigned r = (x & 0xFu) | ((x>>4)&0xF0u) | ((x>>8)&0xF00u) | ((x>>12)&0xF000u);
  unsigned s = (y & 0xFu) | ((y>>4)&0xF0u) | ((y>>8)&0xF00u) | ((y>>12)&0xF000u);
  return r | (s<<16);
}
__device__ __forceinline__ unsigned pk4(unsigned u){
  return ((u & 0xFFu)       ? 1u : 0u) | ((u & 0xFF00u)     ? 2u : 0u)
       | ((u & 0xFF0000u)   ? 4u : 0u) | ((u & 0xFF000000u) ? 8u : 0u);
}

// stage 128x128 raw mask tile -> MB[512] packed bits (coalesced, NT loads, no ballot).
__device__ __forceinline__ void stage_mask_tile(const void* maskp, int mb,
    int gr0, int gc0, unsigned* MB, uint8_t* NB, unsigned* bitsOut, int t){
  if(mb & 2){
    const f32x4* base = (const f32x4*)maskp;
    #pragma unroll
    for(int i=0;i<16;i++){
      int idx = i*256 + t;
      int row = idx >> 5, c4 = idx & 31;
      f32x4 v = __builtin_nontemporal_load(
          &base[((size_t)(gr0+row)*N_T + gc0) / 4 + c4]);
      NB[row*32 + c4] = (uint8_t)((unsigned)(v[0]!=0.f) | ((unsigned)(v[1]!=0.f)<<1)
                                | ((unsigned)(v[2]!=0.f)<<2) | ((unsigned)(v[3]!=0.f)<<3));
    }
  } else if(mb & 1){
    const uint8_t* base = (const uint8_t*)maskp;
    #pragma unroll
    for(int i=0;i<16;i++){
      int idx = i*256 + t;
      int row = idx >> 5, c4 = idx & 31;
      unsigned u = __builtin_nontemporal_load(
          (const unsigned*)&base[(size_t)(gr0+row)*N_T + gc0 + c4*4]);
      NB[row*32 + c4] = (uint8_t)pk4(u);
    }
  } else {
    const i32x4* base = (const i32x4*)maskp;
    #pragma unroll
    for(int i=0;i<16;i++){
      int idx = i*256 + t;
      int row = idx >> 5, c4 = idx & 31;
      i32x4 v = __builtin_nontemporal_load(
          &base[((size_t)(gr0+row)*N_T + gc0) / 4 + c4]);
      NB[row*32 + c4] = (uint8_t)((unsigned)(v[0]!=0) | ((unsigned)(v[1]!=0)<<1)
                                | ((unsigned)(v[2]!=0)<<2) | ((unsigned)(v[3]!=0)<<3));
    }
  }
  __syncthreads();
  if(t < 128){
    uint4 a = *(const uint4*)&NB[t*32];
    uint4 b = *(const uint4*)&NB[t*32 + 16];
    unsigned w0 = nib8(a.x, a.y), w1 = nib8(a.z, a.w);
    unsigned w2 = nib8(b.x, b.y), w3 = nib8(b.z, b.w);
    MB[t*4]   = w0; MB[t*4+1] = w1;
    MB[t*4+2] = w2; MB[t*4+3] = w3;
    if(bitsOut){
      uint4 o; o.x=w0; o.y=w1; o.z=w2; o.w=w3;
      *(uint4*)&bitsOut[(size_t)(gr0 + t)*(N_T/32) + (gc0 >> 5)] = o;
    }
  }
}

// XCD-aware tile decode: each XCD owns a 32-tile et column panel (1 MB, L2-fit)
__device__ __forceinline__ void att_tile(int bid, int& gc0, int& gr0){
  int xcd = bid & 7;
  int idx = bid >> 3;
  gc0 = (xcd*32 + (idx & 31)) * 128;
  gr0 = (idx >> 5) * 128;
}

// fp16 S^T GEMM core: A = et (M=target), B = eq (N=query). 128x128 tile, 4 waves.
__device__ __forceinline__ void qk_gemm(
    const ushort* __restrict__ A16, const ushort* __restrict__ B16,
    int abase, int bbase, int t, ushort* SM, f32x4 (&acc)[4][4]){
  ushort* AB = SM;            // [128][64] swizzled
  ushort* BB = SM + 8192;
  int lane = t & 63;
  int w = t >> 6;
  int wr = w >> 1, wc = w & 1;
  int fr = lane & 15, kg0 = lane >> 4;
  for(int kt=0; kt<2; kt++){
    __syncthreads();
    #pragma unroll
    for(int it=0; it<4; it++){
      int idx = t + it*256;          // 0..1023
      int row = idx >> 3, k8 = idx & 7;
      int sw = (k8 ^ (row & 7)) * 8;
      *(uint4*)&AB[row*64 + sw] = *(const uint4*)&A16[(size_t)(abase+row)*H + kt*64 + k8*8];
      *(uint4*)&BB[row*64 + sw] = *(const uint4*)&B16[(size_t)(bbase+row)*H + kt*64 + k8*8];
    }
    __syncthreads();
    #pragma unroll
    for(int s=0; s<2; s++){
      int kg = s*4 + kg0;
      f16x8 a[4], b[4];
      #pragma unroll
      for(int m=0;m<4;m++){
        int ar = wr*64 + m*16 + fr;
        a[m] = *(const f16x8*)&AB[ar*64 + ((kg ^ (ar & 7)) << 3)];
      }
      #pragma unroll
      for(int n=0;n<4;n++){
        int bc = wc*64 + n*16 + fr;
        b[n] = *(const f16x8*)&BB[bc*64 + ((kg ^ (bc & 7)) << 3)];
      }
      #pragma unroll
      for(int m=0;m<4;m++)
        #pragma unroll
        for(int n=0;n<4;n++)
          acc[m][n] = __builtin_amdgcn_mfma_f32_16x16x32_f16(a[m], b[n], acc[m][n], 0,0,0);
    }
  }
}

// ---------------- attention pass A: raw mask -> bits, GEMM, rowsums ----------------
__global__ __launch_bounds__(256,4) void attsum_k(
    const ushort* __restrict__ eq16, const ushort* __restrict__ et16,
    const void* __restrict__ maskp, const int* __restrict__ flag,
    unsigned* __restrict__ bitsOut, float* __restrict__ rowsum){
  __shared__ ushort SM[2*128*64];       // 32 KB (first 4KB aliased as nibble staging)
  __shared__ __align__(16) unsigned MB[512];
  __shared__ float RS[128][2];
  int t = threadIdx.x;
  int gc0, gr0;
  att_tile(blockIdx.x, gc0, gr0);
  int lane = t & 63;
  int w = t >> 6;
  int wr = w >> 1, wc = w & 1;
  int fr = lane & 15, kg0 = lane >> 4;

  int mb = *flag;
  stage_mask_tile(maskp, mb, gr0, gc0, MB, (uint8_t*)SM, bitsOut, t);

  f32x4 acc[4][4] = {};
  qk_gemm(et16, eq16, gc0, gr0, t, SM, acc);

  const float sc = 0.08838834764831845f;   // 1/sqrt(128)
  #pragma unroll
  for(int n=0;n<4;n++){
    int q = wc*64 + n*16 + fr;
    float s = 0.f;
    #pragma unroll
    for(int m=0;m<4;m++){
      unsigned wb = MB[q*4 + wr*2 + (m>>1)];
      int off = ((m&1)<<4) | (kg0<<2);
      s += ((wb>>(off+0))&1u) ? __expf(acc[m][n][0]*sc) : 0.f;
      s += ((wb>>(off+1))&1u) ? __expf(acc[m][n][1]*sc) : 0.f;
      s += ((wb>>(off+2))&1u) ? __expf(acc[m][n][2]*sc) : 0.f;
      s += ((wb>>(off+3))&1u) ? __expf(acc[m][n][3]*sc) : 0.f;
    }
    s += __shfl_xor(s, 16);
    s += __shfl_xor(s, 32);
    if(lane < 16) RS[q][wr] = s;
  }
  __syncthreads();
  if(t < 128) atomicAdd(&rowsum[gr0 + t], RS[t][0] + RS[t][1]);
}

// ---------------- attention pass B: recompute, normalize, NT float4 store ----------------
__global__ __launch_bounds__(256,4) void attout_k(
    const ushort* __restrict__ eq16, const ushort* __restrict__ et16,
    const void* __restrict__ maskp, const int* __restrict__ flag,
    const unsigned* __restrict__ bitsIn, const float* __restrict__ rowsum,
    float* __restrict__ out){
  __shared__ ushort SM[2*128*64];
  __shared__ __align__(16) unsigned MB[512];
  __shared__ float IRS[128];
  int t = threadIdx.x;
  int gc0, gr0;
  att_tile(blockIdx.x, gc0, gr0);
  int lane = t & 63;
  int w = t >> 6;
  int wr = w >> 1, wc = w & 1;
  int fr = lane & 15, kg0 = lane >> 4;

  if(bitsIn){
    if(t < 128)
      *(uint4*)&MB[t*4] = *(const uint4*)&bitsIn[(size_t)(gr0 + t)*(N_T/32) + (gc0 >> 5)];
  } else {
    int mb = *flag;
    stage_mask_tile(maskp, mb, gr0, gc0, MB, (uint8_t*)SM, nullptr, t);
  }
  if(t < 128) IRS[t] = 1.0f / rowsum[gr0 + t];

  f32x4 acc[4][4] = {};
  qk_gemm(et16, eq16, gc0, gr0, t, SM, acc);

  const float sc = 0.08838834764831845f;
  #pragma unroll
  for(int n=0;n<4;n++){
    int q = wc*64 + n*16 + fr;
    float ir = IRS[q];
    size_t rb = (size_t)(gr0 + q)*N_T + gc0 + wr*64;
    #pragma unroll
    for(int m=0;m<4;m++){
      unsigned wb = MB[q*4 + wr*2 + (m>>1)];
      int off = ((m&1)<<4) | (kg0<<2);
      f32x4 o;
      o[0] = ((wb>>(off+0))&1u) ? __expf(acc[m][n][0]*sc)*ir : 0.f;
      o[1] = ((wb>>(off+1))&1u) ? __expf(acc[m][n][1]*sc)*ir : 0.f;
      o[2] = ((wb>>(off+2))&1u) ? __expf(acc[m][n][2]*sc)*ir : 0.f;
      o[3] = ((wb>>(off+3))&1u) ? __expf(acc[m][n][3]*sc)*ir : 0.f;
      __builtin_nontemporal_store(o, (f32x4*)&out[rb + m*16 + (kg0<<2)]);
    }
  }
}

// ---------------- host launch ----------------
extern "C" void kernel_launch(void* const* d_in, const int* in_sizes, int n_in,
                              void* d_out, int out_size, void* d_ws, size_t ws_size,
                              hipStream_t stream){
  const int* tx  = (const int*)d_in[0];
  const int* qx  = (const int*)d_in[1];
  const int* te  = (const int*)d_in[2];
  const int* qe  = (const int*)d_in[3];
  const void* mask = d_in[4];
  const float* emb = (const float*)d_in[5];
  const float* Wl  = (const float*)d_in[6];
  const float* bl  = (const float*)d_in[7];
  const float* Wr  = (const float*)d_in[8];
  float* out = (float*)d_out;

  // ws layout: features @0, rowsum/flag @9MB, weights @10MB, emb16 @11MB, bits @19MB
  ushort* et16 = (ushort*)d_ws;                       // N_T*H (8 MB)
  ushort* eq16 = et16 + (size_t)N_T*H;                // N_Q*H (1 MB)
  float* rowsum = (float*)((char*)d_ws + ((size_t)9 << 20));
  int*   flag   = (int*)(rowsum + N_Q);
  ushort* WH  = (ushort*)((char*)d_ws + ((size_t)10 << 20));   // NL*128*256 (192 KB)
  ushort* WLo = WH + (size_t)NL*128*256;
  ushort* emb16 = (ushort*)((char*)d_ws + ((size_t)11 << 20)); // VOCAB*H fp16 (256 KB)
  bool useBits = ws_size >= ((size_t)37 << 20);
  unsigned* bits = useBits ? (unsigned*)((char*)d_ws + ((size_t)19 << 20)) : nullptr;

  // phase-1 scratch inside d_out (512MB; fully overwritten by attout at the end)
  char* S = (char*)d_out;
  ushort* xt0  = (ushort*)(S);                         // 8 MB (layer0 out)
  ushort* xt1  = (ushort*)(S + 8388608);               // 8 MB (layer1 out)
  ushort* aggt = (ushort*)(S + 16777216);              // 8 MB
  ushort* xq0  = (ushort*)(S + 25165824);              // 1 MB
  ushort* xq1  = (ushort*)(S + 26214400);              // 1 MB
  ushort* aggq = (ushort*)(S + 27262976);              // 1 MB
  int*   cnt_t = (int*)(S + 28311552);
  int*   rp_t  = cnt_t + N_T;
  int*   pos_t = rp_t + N_T + 1;
  int*   csr_t = pos_t + N_T;
  int*   cnt_q = csr_t + E_T;
  int*   rp_q  = cnt_q + N_Q;
  int*   pos_q = rp_q + N_Q + 1;
  int*   csr_q = pos_q + N_Q;

  init_k<<<320,256,0,stream>>>(cnt_t, cnt_q, rowsum, flag, (const unsigned*)mask,
                               Wl, Wr, WH, WLo, emb, emb16);
  count2_k<<<E_T/256 + E_Q/256,256,0,stream>>>(te, qe, cnt_t, cnt_q);
  scan2_k<<<2,1024,0,stream>>>(cnt_t, rp_t, pos_t, cnt_q, rp_q, pos_q);
  fill2_k<<<E_T/256 + E_Q/256,256,0,stream>>>(te, qe, pos_t, csr_t, pos_q, csr_q);

  ushort* outs_t[NL] = {xt0, xt1, et16};
  ushort* outs_q[NL] = {xq0, xq1, eq16};
  const ushort* cur_t = nullptr;
  const ushort* cur_q = nullptr;
  for(int l=0;l<NL;l++){
    const ushort* wh = WH  + (size_t)l*128*256;
    const ushort* wl = WLo + (size_t)l*128*256;
    const int* nidt = (l==0) ? tx : nullptr;
    const int* nidq = (l==0) ? qx : nullptr;
    agg2_k<<<N_T/4 + N_Q/4,256,0,stream>>>(cur_t, cur_q, nidt, nidq, emb16,
                                           rp_t, csr_t, rp_q, csr_q, aggt, aggq);
    layer2_k<<<N_T/128 + N_Q/128,256,0,stream>>>(aggt, cur_t, nidt, outs_t[l],
                                                 aggq, cur_q, nidq, outs_q[l],
                                                 emb16, wh, wl, bl+(size_t)l*H);
    cur_t = outs_t[l];
    cur_q = outs_q[l];
  }

  attsum_k<<<8192,256,0,stream>>>(eq16, et16, mask, flag, bits, rowsum);
  attout_k<<<8192,256,0,stream>>>(eq16, et16, mask, flag, bits, rowsum, out);
}